// Round 6
// baseline (303.170 us; speedup 1.0000x reference)
//
#include <hip/hip_runtime.h>
#include <hip/hip_bf16.h>

// Effi_MVS: B=1, V=5, C=32, D=48, H=128, W=160, RATIO=8.
// Round 9: R8 audit — the 27-weight contraction was 864 scalar FMAs + 448
// weight VMEM loads per voxel (~60% of VALU, ~70% of VMEM instrs). It is a
// (64x32)·(32x27) GEMM per wave -> moved to 8x mfma_f32_16x16x32_bf16:
//   - gather (unchanged R8 2-tap) produces var[32] -> bf16 -> wave-private
//     LDS rows [256][40] (padded stride, 2-way conflicts only; same-wave DS
//     FIFO => no __syncthreads)
//   - weights pre-laid-out in B-fragment order wfB[2][64][8] by k_setup;
//     2x 16B loads per thread before the gather
//   - C layout (col=tap, row=voxel; m89-verified) -> 8B stores of 4
//     consecutive voxels per (lane, tap)
// k_conv/k_softmax/k_upsample unchanged from R8.

#define NV 5
#define NC 32
#define ND 48
#define NH 128
#define NW 160
#define HW (NH * NW)
#define DHW (ND * HW)

typedef __attribute__((ext_vector_type(2))) float f32x2;
typedef __attribute__((ext_vector_type(4))) float f32x4;
typedef __attribute__((ext_vector_type(2), aligned(4))) float f32x2u;
typedef __attribute__((ext_vector_type(8))) unsigned short u16x8;
typedef __attribute__((ext_vector_type(8))) short short8;
typedef __attribute__((ext_vector_type(4))) unsigned int u32x4;

// ws layout (bytes)
#define OFF_M      0          // float M[4][12]
#define OFF_WF     256        // float wf[32][28] (legacy, unused by K2 now)
#define OFF_DEPTHF 4096       // float depthf[20480]
#define OFF_PRE    86016      // float pre[48*128*160]
#define OFF_WV     4018176    // bf16 WV[27][48*128*160]
#define OFF_WFB    57102336   // bf16 wfB[2][64][8] = 2048 B
// total = 57,104,384 bytes

__device__ __forceinline__ uint32_t pack_bf16(float a, float b) {
  __hip_bfloat16 ba = __float2bfloat16(a), bb = __float2bfloat16(b);
  uint16_t ua, ub;
  __builtin_memcpy(&ua, &ba, 2);
  __builtin_memcpy(&ub, &bb, 2);
  return (uint32_t)ua | ((uint32_t)ub << 16);
}

__device__ __forceinline__ float bf2f(unsigned short u) {
  uint32_t b = ((uint32_t)u) << 16;
  float f;
  __builtin_memcpy(&f, &b, 4);
  return f;
}

// ---------------------------------------------------------------- K1: setup
__global__ void k_setup(const float* __restrict__ proj,
                        const float* __restrict__ wreg,
                        float* __restrict__ M, float* __restrict__ wf,
                        unsigned short* __restrict__ wfB) {
  if (threadIdx.x != 0) return;
  double P[NV][2][4][4];
  for (int v = 0; v < NV; ++v)
    for (int m = 0; m < 2; ++m)
      for (int i = 0; i < 4; ++i)
        for (int j = 0; j < 4; ++j)
          P[v][m][i][j] = (double)proj[((v * 2 + m) * 4 + i) * 4 + j];
  double C[NV][4][4];
  for (int v = 0; v < NV; ++v) {
    for (int i = 0; i < 4; ++i)
      for (int j = 0; j < 4; ++j) C[v][i][j] = P[v][0][i][j];
    for (int i = 0; i < 3; ++i)
      for (int j = 0; j < 4; ++j) {
        double s = 0.0;
        for (int k = 0; k < 3; ++k) s += P[v][1][i][k] * P[v][0][k][j];
        C[v][i][j] = s;
      }
  }
  double a[4][8];
  for (int i = 0; i < 4; ++i)
    for (int j = 0; j < 4; ++j) { a[i][j] = C[0][i][j]; a[i][j + 4] = (i == j) ? 1.0 : 0.0; }
  for (int col = 0; col < 4; ++col) {
    int piv = col; double best = fabs(a[col][col]);
    for (int r = col + 1; r < 4; ++r) { double v = fabs(a[r][col]); if (v > best) { best = v; piv = r; } }
    if (piv != col)
      for (int j = 0; j < 8; ++j) { double t = a[col][j]; a[col][j] = a[piv][j]; a[piv][j] = t; }
    double pv = a[col][col];
    for (int j = 0; j < 8; ++j) a[col][j] /= pv;
    for (int r = 0; r < 4; ++r) if (r != col) {
      double f = a[r][col];
      for (int j = 0; j < 8; ++j) a[r][j] -= f * a[col][j];
    }
  }
  double inv[4][4];
  for (int i = 0; i < 4; ++i)
    for (int j = 0; j < 4; ++j) inv[i][j] = a[i][j + 4];
  for (int v = 1; v < NV; ++v) {
    float* m = M + (v - 1) * 12;
    for (int i = 0; i < 3; ++i) {
      double r[4] = {0, 0, 0, 0};
      for (int k = 0; k < 4; ++k) {
        double cv = C[v][i][k];
        for (int j = 0; j < 4; ++j) r[j] += cv * inv[k][j];
      }
      m[i * 3 + 0] = (float)r[0]; m[i * 3 + 1] = (float)r[1]; m[i * 3 + 2] = (float)r[2];
      m[9 + i] = (float)r[3];
    }
  }
  for (int c = 0; c < NC; ++c) {
    for (int t = 0; t < 27; ++t) wf[c * 28 + t] = wreg[c * 27 + t];
    wf[c * 28 + 27] = 0.f;
  }
  // B-fragment layout for mfma_f32_16x16x32_bf16:
  // lane l supplies col n = l&15, k = (l>>4)*8 + e  (e = 0..7)
  for (int nt = 0; nt < 2; ++nt)
    for (int l = 0; l < 64; ++l)
      for (int e = 0; e < 8; ++e) {
        int tap = nt * 16 + (l & 15);
        int k = (l >> 4) * 8 + e;
        float val = (tap < 27) ? wreg[k * 27 + tap] : 0.f;
        __hip_bfloat16 b = __float2bfloat16(val);
        uint16_t u; __builtin_memcpy(&u, &b, 2);
        wfB[(nt * 64 + l) * 8 + e] = u;
      }
}

// ------------------------------------------- K2: warp + variance + MFMA
__global__ __launch_bounds__(256) void k_warpvar(
    const float* __restrict__ feat,    // [5][32][128][160]
    const float* __restrict__ depthv,  // [48]
    const float* __restrict__ M,       // [4][12]
    const unsigned short* __restrict__ wfB,  // [2][64][8] bf16 fragments
    unsigned short* __restrict__ WVu)  // [27][DHW] bf16
{
  __shared__ unsigned short ldsA[256 * 40];   // [tid][ch], stride 40 (80 B)

  int tid = threadIdx.x;
  int idx = blockIdx.x * 256 + tid;   // [0, DHW)
  int x = idx % NW;
  int t1 = idx / NW;
  int y = t1 % NH;
  int d = t1 / NH;
  int pix = y * NW + x;
  float xf = (float)x, yf = (float)y;
  float df = depthv[d];
  int lane = tid & 63;

  // B fragments (uniform across blocks; 2 x 16B loads, hidden under prologue)
  short8 bfr0 = *(const short8*)(wfB + (size_t)lane * 8);
  short8 bfr1 = *(const short8*)(wfB + (size_t)(64 + lane) * 8);

  int   off[4];
  float wA[4], wB[4];
  bool any4 = false;

#pragma unroll
  for (int v = 0; v < 4; ++v) {
    const float* m = M + v * 12;
    float rx = m[0] * xf + m[1] * yf + m[2];
    float ry = m[3] * xf + m[4] * yf + m[5];
    float rz = m[6] * xf + m[7] * yf + m[8];
    float px = rx * df + m[9];
    float py = ry * df + m[10];
    float pz = rz * df + m[11];
    float gx = px / pz;
    float gy = py / pz;
    float y0 = floorf(gy);
    float wy = gy - y0;
    bool two = (wy == 0.f) || (wy == 1.f);
    any4 = any4 || !two;
    float rowf = (wy == 0.f) ? y0 : (y0 + 1.f);  // single surviving y-row
    float x0 = floorf(gx);
    float wx = gx - x0;
    bool yok  = (rowf >= 0.f) && (rowf <= (float)(NH - 1));
    bool x0ok = (x0 >= 0.f) && (x0 <= (float)(NW - 1)) && yok;
    bool x1ok = (x0 >= -1.f) && (x0 <= (float)(NW - 2)) && yok;
    float rc = fminf(fmaxf(rowf, 0.f), (float)(NH - 1));
    float xc = fminf(fmaxf(x0, 0.f), (float)(NW - 1));
    int xi = (int)xc;
    int o = (int)rc * NW + xi;
    bool ddv = (o == HW - 1);          // absolute plane end: shift base by 1
    bool sv  = (x0 >= 0.f) && (xi <= NW - 2);  // e.y is a distinct valid tap1
    o -= ddv ? 1 : 0;
    float w0 = (1.f - wx) * (x0ok ? 1.f : 0.f);
    float w1 = wx * (x1ok ? 1.f : 0.f);
    float wsum = w0 + w1;
    wA[v] = ddv ? 0.f : (sv ? w0 : wsum);
    wB[v] = ddv ? wsum : (sv ? w1 : 0.f);
    off[v] = o;
  }

  if (__builtin_expect(!any4, 1)) {
    // ---------- hot 2-tap path, 8-channel load batches; var -> bf16 -> LDS
#pragma unroll
    for (int g = 0; g < NC; g += 8) {
      float f0[8];
      f32x2 e[8][4];
#pragma unroll
      for (int cc = 0; cc < 8; ++cc) {
        int c = g + cc;
        f0[cc] = feat[c * HW + pix];
#pragma unroll
        for (int v = 0; v < 4; ++v) {
          const float* fv = feat + ((v + 1) * NC + c) * HW;
          f32x2u t = *(const f32x2u*)(fv + off[v]);
          e[cc][v].x = t.x; e[cc][v].y = t.y;
        }
      }
      float vr[8];
#pragma unroll
      for (int cc = 0; cc < 8; ++cc) {
        float vs = f0[cc], vq = f0[cc] * f0[cc];
#pragma unroll
        for (int v = 0; v < 4; ++v) {
          float val = wA[v] * e[cc][v].x + wB[v] * e[cc][v].y;
          vs += val;
          vq += val * val;
        }
        vr[cc] = vq * 0.2f - (vs * 0.2f) * (vs * 0.2f);
      }
      u32x4 pk;
      pk.x = pack_bf16(vr[0], vr[1]);
      pk.y = pack_bf16(vr[2], vr[3]);
      pk.z = pack_bf16(vr[4], vr[5]);
      pk.w = pack_bf16(vr[6], vr[7]);
      *(u32x4*)(&ldsA[(size_t)tid * 40 + g]) = pk;   // g in ushort units (8/group)
    }
  } else {
    // ---------- general 4-tap fallback (cold)
    int cidx[16]; float cw[16];
#pragma unroll
    for (int v = 0; v < 4; ++v) {
      const float* m = M + v * 12;
      float rx = m[0] * xf + m[1] * yf + m[2];
      float ry = m[3] * xf + m[4] * yf + m[5];
      float rz = m[6] * xf + m[7] * yf + m[8];
      float px = rx * df + m[9];
      float py = ry * df + m[10];
      float pz = rz * df + m[11];
      float gx = px / pz;
      float gy = py / pz;
      float x0 = floorf(gx), y0 = floorf(gy);
      float wx = gx - x0, wy = gy - y0;
      float cxs[2] = {x0, x0 + 1.f}, cys[2] = {y0, y0 + 1.f};
      float wxs[2] = {1.f - wx, wx}, wys[2] = {1.f - wy, wy};
#pragma unroll
      for (int cy = 0; cy < 2; ++cy)
#pragma unroll
        for (int cx = 0; cx < 2; ++cx) {
          float fx = cxs[cx], fy = cys[cy];
          bool valid = (fx >= 0.f) && (fx <= (float)(NW - 1)) &&
                       (fy >= 0.f) && (fy <= (float)(NH - 1));
          float fxc = fminf(fmaxf(fx, 0.f), (float)(NW - 1));
          float fyc = fminf(fmaxf(fy, 0.f), (float)(NH - 1));
          int xi2 = (int)fxc, yi2 = (int)fyc;
          cidx[v * 4 + cy * 2 + cx] = yi2 * NW + xi2;
          cw[v * 4 + cy * 2 + cx] = wxs[cx] * wys[cy] * (valid ? 1.f : 0.f);
        }
    }
    for (int g = 0; g < NC; g += 8) {
      float vr[8];
#pragma unroll
      for (int cc = 0; cc < 8; ++cc) {
        int c = g + cc;
        float f0 = feat[c * HW + pix];
        float vs = f0, vq = f0 * f0;
#pragma unroll
        for (int v = 0; v < 4; ++v) {
          const float* fv = feat + ((v + 1) * NC + c) * HW;
          float val = cw[v * 4 + 0] * fv[cidx[v * 4 + 0]]
                    + cw[v * 4 + 1] * fv[cidx[v * 4 + 1]]
                    + cw[v * 4 + 2] * fv[cidx[v * 4 + 2]]
                    + cw[v * 4 + 3] * fv[cidx[v * 4 + 3]];
          vs += val;
          vq += val * val;
        }
        vr[cc] = vq * 0.2f - (vs * 0.2f) * (vs * 0.2f);
      }
      u32x4 pk;
      pk.x = pack_bf16(vr[0], vr[1]);
      pk.y = pack_bf16(vr[2], vr[3]);
      pk.z = pack_bf16(vr[4], vr[5]);
      pk.w = pack_bf16(vr[6], vr[7]);
      *(u32x4*)(&ldsA[(size_t)tid * 40 + g]) = pk;
    }
  }

  // ---------- MFMA contraction: D[voxel][tap] = var[voxel][k] * W[k][tap]
  // Wave-private: wave reads exactly the 64 rows its own lanes wrote
  // (same-wave DS ops are FIFO; compiler orders potentially-aliasing LDS ops).
  int wb = tid & ~63;                 // wave's first tid in block
  int lrow = lane & 15, lk = lane >> 4;
  uint32_t* W32 = (uint32_t*)WVu;
  int blockbase = blockIdx.x * 256;

#pragma unroll
  for (int m = 0; m < 4; ++m) {
    short8 af = *(const short8*)(&ldsA[(size_t)(wb + m * 16 + lrow) * 40 + lk * 8]);
    f32x4 z = {0.f, 0.f, 0.f, 0.f};
    f32x4 acc0 = __builtin_amdgcn_mfma_f32_16x16x32_bf16(af, bfr0, z, 0, 0, 0);
    f32x4 acc1 = __builtin_amdgcn_mfma_f32_16x16x32_bf16(af, bfr1, z, 0, 0, 0);
    // C layout: col = lane&15 (tap), row = (lane>>4)*4 + reg (voxel)
    int vox = blockbase + wb + m * 16 + lk * 4;
    size_t o0 = ((size_t)lrow * DHW + vox) >> 1;       // u32 index (vox %4==0)
    uint32_t p0 = pack_bf16(acc0[0], acc0[1]);
    uint32_t p1 = pack_bf16(acc0[2], acc0[3]);
    W32[o0] = p0;
    W32[o0 + 1] = p1;
    int tap1 = 16 + lrow;
    if (tap1 < 27) {
      size_t o1 = ((size_t)tap1 * DHW + vox) >> 1;
      uint32_t q0 = pack_bf16(acc1[0], acc1[1]);
      uint32_t q1 = pack_bf16(acc1[2], acc1[3]);
      W32[o1] = q0;
      W32[o1 + 1] = q1;
    }
  }
}

// ------------------------------------------------- K3a: 27-tap gather (conv)
// 8 consecutive-x outputs per thread (R8 version).
__global__ __launch_bounds__(256) void k_conv(const __hip_bfloat16* __restrict__ WV,
                                              float* __restrict__ pre) {
  int t8 = blockIdx.x * 256 + threadIdx.x;   // [0, DHW/8)
  int x8 = (t8 % (NW / 8)) * 8;
  int r = t8 / (NW / 8);
  int y = r % NH;
  int d = r / NH;

  bool lo_ok = (x8 > 0);
  bool hi_ok = (x8 < NW - 8);
  int xlo = lo_ok ? x8 - 2 : 0;
  int xhi = hi_ok ? x8 + 8 : NW - 8;

  float acc[8];
#pragma unroll
  for (int k = 0; k < 8; ++k) acc[k] = 0.f;

#pragma unroll
  for (int dd = 0; dd < 3; ++dd) {
    int dp = d + dd - 1;
    bool dok = (dp >= 0) && (dp < ND);
    int dpc = min(max(dp, 0), ND - 1);
#pragma unroll
    for (int i = 0; i < 3; ++i) {
      int yp = y + i - 1;
      bool yok = (yp >= 0) && (yp < NH);
      int ypc = min(max(yp, 0), NH - 1);
      float gok = (dok && yok) ? 1.f : 0.f;
      const __hip_bfloat16* base =
          WV + (size_t)(dd * 9 + i * 3) * DHW + (size_t)dpc * HW + ypc * NW;

      u16x8 m0 = *(const u16x8*)(base + x8);
      uint32_t l0; __builtin_memcpy(&l0, base + xlo, 4);
      u16x8 m1 = *(const u16x8*)(base + DHW + x8);
      u16x8 m2 = *(const u16x8*)(base + 2 * (size_t)DHW + x8);
      uint32_t h2; __builtin_memcpy(&h2, base + 2 * (size_t)DHW + xhi, 4);

      float em1 = lo_ok ? bf2f((unsigned short)(l0 >> 16)) : 0.f;
      float e8  = hi_ok ? bf2f((unsigned short)(h2 & 0xffff)) : 0.f;

      acc[0] += gok * (em1 + bf2f(m1[0]) + bf2f(m2[1]));
#pragma unroll
      for (int k = 1; k < 7; ++k)
        acc[k] += gok * (bf2f(m0[k - 1]) + bf2f(m1[k]) + bf2f(m2[k + 1]));
      acc[7] += gok * (bf2f(m0[6]) + bf2f(m1[7]) + e8);
    }
  }

  float* op = pre + (size_t)d * HW + y * NW + x8;
  f32x4 lo4, hi4;
  lo4.x = acc[0]; lo4.y = acc[1]; lo4.z = acc[2]; lo4.w = acc[3];
  hi4.x = acc[4]; hi4.y = acc[5]; hi4.z = acc[6]; hi4.w = acc[7];
  *(f32x4*)op = lo4;
  *(f32x4*)(op + 4) = hi4;
}

// ---------------------------------------- K3b: softmax over D + depth + conf
__global__ __launch_bounds__(256) void k_softmax(const float* __restrict__ pre,
                                                 const float* __restrict__ depthv,
                                                 float* __restrict__ depthf,
                                                 float* __restrict__ out_depth,
                                                 float* __restrict__ out_conf) {
  int p = blockIdx.x * 256 + threadIdx.x;
  float pr[ND];
  float m = -1e30f;
#pragma unroll
  for (int d = 0; d < ND; ++d) { pr[d] = pre[d * HW + p]; m = fmaxf(m, pr[d]); }
  float s = 0.f;
#pragma unroll
  for (int d = 0; d < ND; ++d) { pr[d] = expf(pr[d] - m); s += pr[d]; }
  float inv = 1.f / s;
  float dep = 0.f, ti = 0.f;
#pragma unroll
  for (int d = 0; d < ND; ++d) {
    float prob = pr[d] * inv;
    pr[d] = prob;
    dep += prob * depthv[d];
    ti += prob * (float)d;
  }
  int di = (int)ti;
  di = di < 0 ? 0 : (di > ND - 1 ? ND - 1 : di);
  float conf = 0.f;
#pragma unroll
  for (int d = 0; d < ND; ++d)
    conf += (d >= di - 1 && d <= di + 2) ? pr[d] : 0.f;
  depthf[p] = dep;
  out_depth[p] = dep;
  out_conf[p] = conf;
}

// -------------------------------------------------- K4: convex upsample (x8)
__global__ __launch_bounds__(256) void k_upsample(const float* __restrict__ mask,
                                                  const float* __restrict__ depthf,
                                                  float* __restrict__ out) {
  int idx = blockIdx.x * 256 + threadIdx.x;  // [0, HW*8)
  int x = idx % NW;
  int r = idx / NW;
  int y = r % NH;
  int dy = r / NH;                           // 0..7
  int pix = y * NW + x;

  float dv[9];
#pragma unroll
  for (int k = 0; k < 9; ++k) {
    int ky = y + k / 3 - 1;
    int kx = x + k % 3 - 1;
    bool ok = (ky >= 0) && (ky < NH) && (kx >= 0) && (kx < NW);
    int kyc = min(max(ky, 0), NH - 1);
    int kxc = min(max(kx, 0), NW - 1);
    float t = depthf[kyc * NW + kxc];
    dv[k] = ok ? t : 0.f;
  }

  float res[8];
#pragma unroll
  for (int dx = 0; dx < 8; ++dx) {
    float mv[9];
    float mmax = -1e30f;
#pragma unroll
    for (int k = 0; k < 9; ++k) {
      mv[k] = mask[(size_t)(k * 64 + dy * 8 + dx) * HW + pix];
      mmax = fmaxf(mmax, mv[k]);
    }
    float s = 0.f, acc = 0.f;
#pragma unroll
    for (int k = 0; k < 9; ++k) {
      float e = expf(mv[k] - mmax);
      s += e;
      acc += e * dv[k];
    }
    res[dx] = acc / s;
  }

  float* op = out + (size_t)(y * 8 + dy) * (NW * 8) + x * 8;
  f32x4 lo, hi;
  lo.x = res[0]; lo.y = res[1]; lo.z = res[2]; lo.w = res[3];
  hi.x = res[4]; hi.y = res[5]; hi.z = res[6]; hi.w = res[7];
  *(f32x4*)op = lo;
  *(f32x4*)(op + 4) = hi;
}

// ---------------------------------------------------------------- launcher
extern "C" void kernel_launch(void* const* d_in, const int* in_sizes, int n_in,
                              void* d_out, int out_size, void* d_ws, size_t ws_size,
                              hipStream_t stream) {
  const float* feat   = (const float*)d_in[0];
  const float* proj   = (const float*)d_in[1];
  const float* depthv = (const float*)d_in[2];
  const float* mask   = (const float*)d_in[3];
  const float* wreg   = (const float*)d_in[4];

  char* ws = (char*)d_ws;
  float* M       = (float*)(ws + OFF_M);
  float* wf      = (float*)(ws + OFF_WF);
  float* depthf  = (float*)(ws + OFF_DEPTHF);
  float* pre     = (float*)(ws + OFF_PRE);
  unsigned short* WVu = (unsigned short*)(ws + OFF_WV);
  unsigned short* wfB = (unsigned short*)(ws + OFF_WFB);
  const __hip_bfloat16* WV = (const __hip_bfloat16*)(ws + OFF_WV);

  float* out = (float*)d_out;
  float* out_depth = out + (NH * 8) * (NW * 8);
  float* out_conf  = out_depth + HW;

  k_setup<<<1, 64, 0, stream>>>(proj, wreg, M, wf, wfB);
  k_warpvar<<<DHW / 256, 256, 0, stream>>>(feat, depthv, M, wfB, WVu);
  k_conv<<<(DHW / 8) / 256, 256, 0, stream>>>(WV, pre);
  k_softmax<<<HW / 256, 256, 0, stream>>>(pre, depthv, depthf, out_depth, out_conf);
  k_upsample<<<(NH * 8 * NW * 8 / 8) / 256, 256, 0, stream>>>(mask, depthf, out);
}

// Round 7
// 227.387 us; speedup vs baseline: 1.3333x; 1.3333x over previous
//
#include <hip/hip_runtime.h>
#include <hip/hip_bf16.h>

// Effi_MVS: B=1, V=5, C=32, D=48, H=128, W=160, RATIO=8.
// Round 10: R9 MFMA regressed (occupancy 9%, MfmaUtil 0.45% — contraction
// FMAs were never the limit; stalls are). Ledger across rounds says the
// "other" kernels total ~102-115us and scalar k_conv (3840 blk) beats the
// 8-wide one (480 blk) by ~13us: TLP > per-thread efficiency, again.
//   - k_warpvar: R8 structure + REAL software pipeline: 8 groups x 4 ch,
//     alternating named reg sets (A/B), sched_barrier(0) pins ~20 loads in
//     flight ahead of each compute phase (R8's batch was collapsed: VGPR 68).
//   - k_conv: revert to proven scalar 27-tap version (DHW threads).
//   - k_upsample: 2 dx per thread -> 40 waves/CU, 27 coalesced loads.

#define NV 5
#define NC 32
#define ND 48
#define NH 128
#define NW 160
#define HW (NH * NW)
#define DHW (ND * HW)

typedef __attribute__((ext_vector_type(2))) float f32x2;
typedef __attribute__((ext_vector_type(4))) float f32x4;
typedef __attribute__((ext_vector_type(2), aligned(4))) float f32x2u;

// ws layout (bytes)
#define OFF_M      0          // float M[4][12]
#define OFF_WF     256        // float wf[32][28]
#define OFF_DEPTHF 4096       // float depthf[20480]
#define OFF_PRE    86016      // float pre[48*128*160]
#define OFF_WV     4018176    // bf16 WV[27][48*128*160]
// total = 57,102,336 bytes

// ---------------------------------------------------------------- K1: setup
__global__ void k_setup(const float* __restrict__ proj,
                        const float* __restrict__ wreg,
                        float* __restrict__ M, float* __restrict__ wf) {
  if (threadIdx.x != 0) return;
  double P[NV][2][4][4];
  for (int v = 0; v < NV; ++v)
    for (int m = 0; m < 2; ++m)
      for (int i = 0; i < 4; ++i)
        for (int j = 0; j < 4; ++j)
          P[v][m][i][j] = (double)proj[((v * 2 + m) * 4 + i) * 4 + j];
  double C[NV][4][4];
  for (int v = 0; v < NV; ++v) {
    for (int i = 0; i < 4; ++i)
      for (int j = 0; j < 4; ++j) C[v][i][j] = P[v][0][i][j];
    for (int i = 0; i < 3; ++i)
      for (int j = 0; j < 4; ++j) {
        double s = 0.0;
        for (int k = 0; k < 3; ++k) s += P[v][1][i][k] * P[v][0][k][j];
        C[v][i][j] = s;
      }
  }
  double a[4][8];
  for (int i = 0; i < 4; ++i)
    for (int j = 0; j < 4; ++j) { a[i][j] = C[0][i][j]; a[i][j + 4] = (i == j) ? 1.0 : 0.0; }
  for (int col = 0; col < 4; ++col) {
    int piv = col; double best = fabs(a[col][col]);
    for (int r = col + 1; r < 4; ++r) { double v = fabs(a[r][col]); if (v > best) { best = v; piv = r; } }
    if (piv != col)
      for (int j = 0; j < 8; ++j) { double t = a[col][j]; a[col][j] = a[piv][j]; a[piv][j] = t; }
    double pv = a[col][col];
    for (int j = 0; j < 8; ++j) a[col][j] /= pv;
    for (int r = 0; r < 4; ++r) if (r != col) {
      double f = a[r][col];
      for (int j = 0; j < 8; ++j) a[r][j] -= f * a[col][j];
    }
  }
  double inv[4][4];
  for (int i = 0; i < 4; ++i)
    for (int j = 0; j < 4; ++j) inv[i][j] = a[i][j + 4];
  for (int v = 1; v < NV; ++v) {
    float* m = M + (v - 1) * 12;
    for (int i = 0; i < 3; ++i) {
      double r[4] = {0, 0, 0, 0};
      for (int k = 0; k < 4; ++k) {
        double cv = C[v][i][k];
        for (int j = 0; j < 4; ++j) r[j] += cv * inv[k][j];
      }
      m[i * 3 + 0] = (float)r[0]; m[i * 3 + 1] = (float)r[1]; m[i * 3 + 2] = (float)r[2];
      m[9 + i] = (float)r[3];
    }
  }
  for (int c = 0; c < NC; ++c) {
    for (int t = 0; t < 27; ++t) wf[c * 28 + t] = wreg[c * 27 + t];
    wf[c * 28 + 27] = 0.f;
  }
}

// ------------------------------------------- K2: warp + variance + contract
struct Grp {
  float f0[4];
  f32x2 e[4][4];   // [cc][view]
};

__device__ __forceinline__ void loadg(const float* __restrict__ feat, int pix,
                                      const int* off, int g, Grp& r) {
#pragma unroll
  for (int cc = 0; cc < 4; ++cc) {
    int c = g * 4 + cc;
    r.f0[cc] = feat[c * HW + pix];
#pragma unroll
    for (int v = 0; v < 4; ++v) {
      const float* fv = feat + ((v + 1) * NC + c) * HW;
      f32x2u t = *(const f32x2u*)(fv + off[v]);
      r.e[cc][v].x = t.x; r.e[cc][v].y = t.y;
    }
  }
}

__device__ __forceinline__ void compg(const float* __restrict__ wf,
                                      const float* wA, const float* wB,
                                      int g, const Grp& r, f32x2* wv) {
#pragma unroll
  for (int cc = 0; cc < 4; ++cc) {
    int c = g * 4 + cc;
    float vs = r.f0[cc], vq = r.f0[cc] * r.f0[cc];
#pragma unroll
    for (int v = 0; v < 4; ++v) {
      float val = wA[v] * r.e[cc][v].x + wB[v] * r.e[cc][v].y;
      vs += val;
      vq += val * val;
    }
    float var = vq * 0.2f - (vs * 0.2f) * (vs * 0.2f);
    const f32x2* wrow = (const f32x2*)(wf + c * 28);
    f32x2 vv; vv.x = var; vv.y = var;
#pragma unroll
    for (int u = 0; u < 14; ++u) wv[u] += wrow[u] * vv;
  }
}

__global__ __launch_bounds__(256) void k_warpvar(
    const float* __restrict__ feat,    // [5][32][128][160]
    const float* __restrict__ depthv,  // [48]
    const float* __restrict__ M,       // [4][12]
    const float* __restrict__ wf,      // [32][28]
    __hip_bfloat16* __restrict__ WV)   // [27][DHW]
{
  int idx = blockIdx.x * 256 + threadIdx.x;   // [0, DHW)
  int x = idx % NW;
  int t1 = idx / NW;
  int y = t1 % NH;
  int d = t1 / NH;
  int pix = y * NW + x;
  float xf = (float)x, yf = (float)y;
  float df = depthv[d];

  int   off[4];
  float wA[4], wB[4];
  bool any4 = false;

#pragma unroll
  for (int v = 0; v < 4; ++v) {
    const float* m = M + v * 12;
    float rx = m[0] * xf + m[1] * yf + m[2];
    float ry = m[3] * xf + m[4] * yf + m[5];
    float rz = m[6] * xf + m[7] * yf + m[8];
    float px = rx * df + m[9];
    float py = ry * df + m[10];
    float pz = rz * df + m[11];
    float gx = px / pz;
    float gy = py / pz;
    float y0 = floorf(gy);
    float wy = gy - y0;
    bool two = (wy == 0.f) || (wy == 1.f);
    any4 = any4 || !two;
    float rowf = (wy == 0.f) ? y0 : (y0 + 1.f);  // single surviving y-row
    float x0 = floorf(gx);
    float wx = gx - x0;
    bool yok  = (rowf >= 0.f) && (rowf <= (float)(NH - 1));
    bool x0ok = (x0 >= 0.f) && (x0 <= (float)(NW - 1)) && yok;
    bool x1ok = (x0 >= -1.f) && (x0 <= (float)(NW - 2)) && yok;
    float rc = fminf(fmaxf(rowf, 0.f), (float)(NH - 1));
    float xc = fminf(fmaxf(x0, 0.f), (float)(NW - 1));
    int xi = (int)xc;
    int o = (int)rc * NW + xi;
    bool ddv = (o == HW - 1);          // absolute plane end: shift base by 1
    bool sv  = (x0 >= 0.f) && (xi <= NW - 2);  // e.y is a distinct valid tap1
    o -= ddv ? 1 : 0;
    float w0 = (1.f - wx) * (x0ok ? 1.f : 0.f);
    float w1 = wx * (x1ok ? 1.f : 0.f);
    float wsum = w0 + w1;
    wA[v] = ddv ? 0.f : (sv ? w0 : wsum);
    wB[v] = ddv ? wsum : (sv ? w1 : 0.f);
    off[v] = o;
  }

  f32x2 wv[14];
#pragma unroll
  for (int u = 0; u < 14; ++u) { wv[u].x = 0.f; wv[u].y = 0.f; }

  if (__builtin_expect(any4, 0)) {
    // ---------- general 4-tap fallback (cold). v/u unrolled, c rolled.
    int cidx[16]; float cw[16];
#pragma unroll
    for (int v = 0; v < 4; ++v) {
      const float* m = M + v * 12;
      float rx = m[0] * xf + m[1] * yf + m[2];
      float ry = m[3] * xf + m[4] * yf + m[5];
      float rz = m[6] * xf + m[7] * yf + m[8];
      float px = rx * df + m[9];
      float py = ry * df + m[10];
      float pz = rz * df + m[11];
      float gx = px / pz;
      float gy = py / pz;
      float x0 = floorf(gx), y0 = floorf(gy);
      float wx = gx - x0, wy = gy - y0;
      float cxs[2] = {x0, x0 + 1.f}, cys[2] = {y0, y0 + 1.f};
      float wxs[2] = {1.f - wx, wx}, wys[2] = {1.f - wy, wy};
#pragma unroll
      for (int cy = 0; cy < 2; ++cy)
#pragma unroll
        for (int cx = 0; cx < 2; ++cx) {
          float fx = cxs[cx], fy = cys[cy];
          bool valid = (fx >= 0.f) && (fx <= (float)(NW - 1)) &&
                       (fy >= 0.f) && (fy <= (float)(NH - 1));
          float fxc = fminf(fmaxf(fx, 0.f), (float)(NW - 1));
          float fyc = fminf(fmaxf(fy, 0.f), (float)(NH - 1));
          int xi2 = (int)fxc, yi2 = (int)fyc;
          cidx[v * 4 + cy * 2 + cx] = yi2 * NW + xi2;
          cw[v * 4 + cy * 2 + cx] = wxs[cx] * wys[cy] * (valid ? 1.f : 0.f);
        }
    }
    for (int c = 0; c < NC; ++c) {
      float f0 = feat[c * HW + pix];
      float vs = f0, vq = f0 * f0;
#pragma unroll
      for (int v = 0; v < 4; ++v) {
        const float* fv = feat + ((v + 1) * NC + c) * HW;
        float val = cw[v * 4 + 0] * fv[cidx[v * 4 + 0]]
                  + cw[v * 4 + 1] * fv[cidx[v * 4 + 1]]
                  + cw[v * 4 + 2] * fv[cidx[v * 4 + 2]]
                  + cw[v * 4 + 3] * fv[cidx[v * 4 + 3]];
        vs += val;
        vq += val * val;
      }
      float var = vq * 0.2f - (vs * 0.2f) * (vs * 0.2f);
      const f32x2* wrow = (const f32x2*)(wf + c * 28);
      f32x2 vv; vv.x = var; vv.y = var;
#pragma unroll
      for (int u = 0; u < 14; ++u) wv[u] += wrow[u] * vv;
    }
  } else {
    // ---------- hot 2-tap path, software-pipelined: load(g+1) || compute(g)
    Grp A, B;
    loadg(feat, pix, off, 0, A);
    loadg(feat, pix, off, 1, B);
    __builtin_amdgcn_sched_barrier(0);
    compg(wf, wA, wB, 0, A, wv);
    loadg(feat, pix, off, 2, A);
    __builtin_amdgcn_sched_barrier(0);
    compg(wf, wA, wB, 1, B, wv);
    loadg(feat, pix, off, 3, B);
    __builtin_amdgcn_sched_barrier(0);
    compg(wf, wA, wB, 2, A, wv);
    loadg(feat, pix, off, 4, A);
    __builtin_amdgcn_sched_barrier(0);
    compg(wf, wA, wB, 3, B, wv);
    loadg(feat, pix, off, 5, B);
    __builtin_amdgcn_sched_barrier(0);
    compg(wf, wA, wB, 4, A, wv);
    loadg(feat, pix, off, 6, A);
    __builtin_amdgcn_sched_barrier(0);
    compg(wf, wA, wB, 5, B, wv);
    loadg(feat, pix, off, 7, B);
    __builtin_amdgcn_sched_barrier(0);
    compg(wf, wA, wB, 6, A, wv);
    __builtin_amdgcn_sched_barrier(0);
    compg(wf, wA, wB, 7, B, wv);
  }

#pragma unroll
  for (int u = 0; u < 14; ++u) {
    int t0 = 2 * u;
    WV[t0 * DHW + idx] = __float2bfloat16(wv[u].x);
    if (t0 + 1 < 27) WV[(t0 + 1) * DHW + idx] = __float2bfloat16(wv[u].y);
  }
}

// ------------------------------------------------- K3a: 27-tap gather (conv)
// Scalar version (proven fastest: 3840 blocks, TLP-rich).
__global__ __launch_bounds__(256) void k_conv(const __hip_bfloat16* __restrict__ WV,
                                              float* __restrict__ pre) {
  int idx = blockIdx.x * 256 + threadIdx.x;
  int x = idx % NW;
  int t1 = idx / NW;
  int y = t1 % NH;
  int d = t1 / NH;
  float acc = 0.f;
#pragma unroll
  for (int dd = 0; dd < 3; ++dd) {
    int dp = d + dd - 1;
    bool dok = (dp >= 0) && (dp < ND);
    int dpc = min(max(dp, 0), ND - 1);
#pragma unroll
    for (int i = 0; i < 3; ++i) {
      int yp = y + i - 1;
      bool yok = (yp >= 0) && (yp < NH);
      int ypc = min(max(yp, 0), NH - 1);
#pragma unroll
      for (int j = 0; j < 3; ++j) {
        int xp = x + j - 1;
        bool xok = (xp >= 0) && (xp < NW);
        int xpc = min(max(xp, 0), NW - 1);
        int t = dd * 9 + i * 3 + j;
        float v = __bfloat162float(WV[t * DHW + dpc * HW + ypc * NW + xpc]);
        acc += (dok && yok && xok) ? v : 0.f;
      }
    }
  }
  pre[idx] = acc;
}

// ---------------------------------------- K3b: softmax over D + depth + conf
__global__ __launch_bounds__(256) void k_softmax(const float* __restrict__ pre,
                                                 const float* __restrict__ depthv,
                                                 float* __restrict__ depthf,
                                                 float* __restrict__ out_depth,
                                                 float* __restrict__ out_conf) {
  int p = blockIdx.x * 256 + threadIdx.x;
  float pr[ND];
  float m = -1e30f;
#pragma unroll
  for (int d = 0; d < ND; ++d) { pr[d] = pre[d * HW + p]; m = fmaxf(m, pr[d]); }
  float s = 0.f;
#pragma unroll
  for (int d = 0; d < ND; ++d) { pr[d] = expf(pr[d] - m); s += pr[d]; }
  float inv = 1.f / s;
  float dep = 0.f, ti = 0.f;
#pragma unroll
  for (int d = 0; d < ND; ++d) {
    float prob = pr[d] * inv;
    pr[d] = prob;
    dep += prob * depthv[d];
    ti += prob * (float)d;
  }
  int di = (int)ti;
  di = di < 0 ? 0 : (di > ND - 1 ? ND - 1 : di);
  float conf = 0.f;
#pragma unroll
  for (int d = 0; d < ND; ++d)
    conf += (d >= di - 1 && d <= di + 2) ? pr[d] : 0.f;
  depthf[p] = dep;
  out_depth[p] = dep;
  out_conf[p] = conf;
}

// -------------------------------------------------- K4: convex upsample (x8)
// 2 dx per thread: 40 waves/CU, 27 coalesced loads/thread.
__global__ __launch_bounds__(256) void k_upsample(const float* __restrict__ mask,
                                                  const float* __restrict__ depthf,
                                                  float* __restrict__ out) {
  int idx = blockIdx.x * 256 + threadIdx.x;  // [0, HW*32)
  int pix = idx % HW;
  int g = idx / HW;                          // 0..31
  int dy = g >> 2;
  int dx0 = (g & 3) * 2;
  int x = pix % NW;
  int y = pix / NW;

  float dv[9];
#pragma unroll
  for (int k = 0; k < 9; ++k) {
    int ky = y + k / 3 - 1;
    int kx = x + k % 3 - 1;
    bool ok = (ky >= 0) && (ky < NH) && (kx >= 0) && (kx < NW);
    int kyc = min(max(ky, 0), NH - 1);
    int kxc = min(max(kx, 0), NW - 1);
    float t = depthf[kyc * NW + kxc];
    dv[k] = ok ? t : 0.f;
  }

  float res[2];
#pragma unroll
  for (int j = 0; j < 2; ++j) {
    int dx = dx0 + j;
    float mv[9];
    float mmax = -1e30f;
#pragma unroll
    for (int k = 0; k < 9; ++k) {
      mv[k] = mask[(size_t)(k * 64 + dy * 8 + dx) * HW + pix];
      mmax = fmaxf(mmax, mv[k]);
    }
    float s = 0.f, acc = 0.f;
#pragma unroll
    for (int k = 0; k < 9; ++k) {
      float e = expf(mv[k] - mmax);
      s += e;
      acc += e * dv[k];
    }
    res[j] = acc / s;
  }

  float* op = out + (size_t)(y * 8 + dy) * (NW * 8) + x * 8 + dx0;
  f32x2 r2; r2.x = res[0]; r2.y = res[1];
  *(f32x2*)op = r2;
}

// ---------------------------------------------------------------- launcher
extern "C" void kernel_launch(void* const* d_in, const int* in_sizes, int n_in,
                              void* d_out, int out_size, void* d_ws, size_t ws_size,
                              hipStream_t stream) {
  const float* feat   = (const float*)d_in[0];
  const float* proj   = (const float*)d_in[1];
  const float* depthv = (const float*)d_in[2];
  const float* mask   = (const float*)d_in[3];
  const float* wreg   = (const float*)d_in[4];

  char* ws = (char*)d_ws;
  float* M       = (float*)(ws + OFF_M);
  float* wf      = (float*)(ws + OFF_WF);
  float* depthf  = (float*)(ws + OFF_DEPTHF);
  float* pre     = (float*)(ws + OFF_PRE);
  __hip_bfloat16* WV = (__hip_bfloat16*)(ws + OFF_WV);

  float* out = (float*)d_out;
  float* out_depth = out + (NH * 8) * (NW * 8);
  float* out_conf  = out_depth + HW;

  k_setup<<<1, 64, 0, stream>>>(proj, wreg, M, wf);
  k_warpvar<<<DHW / 256, 256, 0, stream>>>(feat, depthv, M, wf, WV);
  k_conv<<<DHW / 256, 256, 0, stream>>>(WV, pre);
  k_softmax<<<HW / 256, 256, 0, stream>>>(pre, depthv, depthf, out_depth, out_conf);
  k_upsample<<<(HW * 32) / 256, 256, 0, stream>>>(mask, depthf, out);
}